// Round 16
// baseline (183.257 us; speedup 1.0000x reference)
//
#include <hip/hip_runtime.h>
#include <hip/hip_bf16.h>
#include <math.h>

// CommNetWork fused MFMA kernel v8, MI355X gfx950. fp32 in / fp32 out.
// v7 post-mortem: __launch_bounds__(1024, 4) did NOT raise the VGPR cap -
// VGPR_Count stayed 64, spill identical to v6 (142MB FETCH / 260MB WRITE),
// dispatch ~110us. Consistent with CUDA min-blocks semantics: 4 blocks x 16
// waves = 64 waves/CU -> clamp 8 waves/SIMD -> 64 VGPR. v8 pins the backend
// attribute directly: __attribute__((amdgpu_waves_per_eu(4,4))) -> min=max=4
// waves/EU -> VGPR budget 512/4 = 128. The identical body measured 116 VGPR
// at 512 thr (v5), so it fits with zero spill. TLP structure unchanged:
// 1024 thr = 16 waves = 4 waves/SIMD, one 16-col pass per wave.
// [Rounds 12-15: resubmitted verbatim - benches hit GPUAcquisitionTimeout;
//  the v8 experiment has not yet been measured.]

typedef __bf16  bf16x8 __attribute__((ext_vector_type(8)));
typedef float   f32x4  __attribute__((ext_vector_type(4)));

#define DIN 128
#define H0  256
#define SW  264   // padded stride, 256-wide tiles: 132 dwords = 4 mod 32 banks
#define SWO 136   // padded stride, 128-wide obs tile
#define LOG2E 1.44269504088896f

// ws element offsets (bf16) for converted weight matrices
#define O_WENC 0
#define O_WOBS 32768
#define O_WIH  98304
#define O_WHH  294912
#define O_WVAL 491520
#define O_WDEC 557056
#define W_TOT  573440   // elements; ws bytes needed = 1146880

__device__ __forceinline__ f32x4 mfma16(bf16x8 a, bf16x8 b, f32x4 c) {
    return __builtin_amdgcn_mfma_f32_16x16x32_bf16(a, b, c, 0, 0, 0);
}
__device__ __forceinline__ float bf2f(__hip_bfloat16 x) { return __bfloat162float(x); }
__device__ __forceinline__ __hip_bfloat16 f2bf(float x) { return __float2bfloat16(x); }

__device__ __forceinline__ float fsigmoid(float x) {
    float e = __builtin_amdgcn_exp2f(-LOG2E * x);
    return __builtin_amdgcn_rcpf(1.0f + e);
}
__device__ __forceinline__ float ftanh(float x) {
    float e = __builtin_amdgcn_exp2f(2.0f * LOG2E * x);
    return 1.0f - 2.0f * __builtin_amdgcn_rcpf(1.0f + e);
}

__device__ __forceinline__ bf16x8 w8(const __hip_bfloat16* p, int idx) {
    return *(const bf16x8*)(p + idx);
}

// affine tile addressing (padded stride)
__device__ __forceinline__ int tadr(int r, int k) { return r * SW + k; }
__device__ __forceinline__ int oadr(int r, int k) { return r * SWO + k; }

// ---- prep: convert 6 weight matrices fp32 -> bf16 into ws (vectorized) ----
__global__ __launch_bounds__(256) void prep_kernel(
    const float* __restrict__ W_enc, const float* __restrict__ W_obs,
    const float* __restrict__ W_ih,  const float* __restrict__ W_hh,
    const float* __restrict__ W_val, const float* __restrict__ W_dec,
    __hip_bfloat16* __restrict__ ws)
{
    const int i = (blockIdx.x * 256 + threadIdx.x) * 8;
    if (i >= W_TOT) return;
    const float* src; int off;
    if      (i < O_WOBS) { src = W_enc; off = O_WENC; }
    else if (i < O_WIH)  { src = W_obs; off = O_WOBS; }
    else if (i < O_WHH)  { src = W_ih;  off = O_WIH;  }
    else if (i < O_WVAL) { src = W_hh;  off = O_WHH;  }
    else if (i < O_WDEC) { src = W_val; off = O_WVAL; }
    else                 { src = W_dec; off = O_WDEC; }
    const float* f = src + (i - off);
    f32x4 a = *(const f32x4*)f;
    f32x4 b = *(const f32x4*)(f + 4);
    bf16x8 v;
    #pragma unroll
    for (int j = 0; j < 4; j++) { v[j] = (__bf16)a[j]; v[j + 4] = (__bf16)b[j]; }
    *(bf16x8*)(ws + i) = v;
}

__global__ __launch_bounds__(1024)
__attribute__((amdgpu_waves_per_eu(4, 4)))
void commnet_mfma(
    const __hip_bfloat16* __restrict__ ws,
    const float* __restrict__ b_enc, const float* __restrict__ b_obs,
    const float* __restrict__ b_ih,  const float* __restrict__ b_hh,
    const float* __restrict__ b_val, const float* __restrict__ b_dec,
    const float* __restrict__ obs,   float* __restrict__ out)
{
    __shared__ __align__(16) __hip_bfloat16 T0[64 * SW];  // X1 -> h'
    __shared__ __align__(16) __hip_bfloat16 T1[64 * SW];  // obs -> H -> V

    const __hip_bfloat16* W_enc = ws + O_WENC;
    const __hip_bfloat16* W_obs = ws + O_WOBS;
    const __hip_bfloat16* W_ih  = ws + O_WIH;
    const __hip_bfloat16* W_hh  = ws + O_WHH;
    const __hip_bfloat16* W_val = ws + O_WVAL;
    const __hip_bfloat16* W_dec = ws + O_WDEC;

    const int tid  = threadIdx.x;
    const int wave = tid >> 6;           // 0..15: column-tile owner
    const int lane = tid & 63;
    const int quad = lane >> 4;
    const int lc   = lane & 15;          // tile col (n) / A-frag row (m)
    const int row0 = blockIdx.x * 64;    // global row base for this batch
    const int ko16 = quad * 8;           // k offset of this lane's fragment
    const int n    = wave * 16 + lc;     // this wave's output column (256-wide stages)

    // ---- stage obs (fp32 global) -> bf16 padded T1 (1 iter/thread) ----
    {
        const int i = tid;               // 1024 threads, 1024 chunks
        const int r = i >> 4;
        const int c = (i & 15) << 3;
        const float* src = obs + (row0 + r) * DIN + c;
        f32x4 a = *(const f32x4*)src;
        f32x4 b = *(const f32x4*)(src + 4);
        bf16x8 v;
        #pragma unroll
        for (int j = 0; j < 4; j++) { v[j] = (__bf16)a[j]; v[j + 4] = (__bf16)b[j]; }
        *(bf16x8*)&T1[oadr(r, c)] = v;
    }
    __syncthreads();

    // ---- stage 1: X1 = relu(obs @ W_enc^T + b_enc) -> T0 ----
    {
        const float bias = b_enc[n];
        f32x4 acc[4] = {};
        #pragma unroll
        for (int k0 = 0; k0 < DIN; k0 += 32) {
            const int kk = k0 + ko16;
            bf16x8 b = w8(W_enc, n * DIN + kk);
            #pragma unroll
            for (int rt = 0; rt < 4; rt++) {
                bf16x8 a = *(const bf16x8*)&T1[oadr(rt * 16 + lc, kk)];
                acc[rt] = mfma16(a, b, acc[rt]);
            }
        }
        #pragma unroll
        for (int rt = 0; rt < 4; rt++)
            #pragma unroll
            for (int i = 0; i < 4; i++) {
                const int row = rt * 16 + quad * 4 + i;
                T0[tadr(row, n)] = f2bf(fmaxf(acc[rt][i] + bias, 0.0f));
            }
    }
    __syncthreads();

    // ---- stage 2: H = X1 @ W_obs^T + b_obs -> T1 (obs dead) ----
    {
        const float bias = b_obs[n];
        f32x4 acc[4] = {};
        #pragma unroll
        for (int k0 = 0; k0 < H0; k0 += 32) {
            const int kk = k0 + ko16;
            bf16x8 b = w8(W_obs, n * H0 + kk);
            #pragma unroll
            for (int rt = 0; rt < 4; rt++) {
                bf16x8 a = *(const bf16x8*)&T0[tadr(rt * 16 + lc, kk)];
                acc[rt] = mfma16(a, b, acc[rt]);
            }
        }
        #pragma unroll
        for (int rt = 0; rt < 4; rt++)
            #pragma unroll
            for (int i = 0; i < 4; i++) {
                const int row = rt * 16 + quad * 4 + i;
                T1[tadr(row, n)] = f2bf(acc[rt][i] + bias);
            }
    }
    __syncthreads();

    // ---- GRU with folded comm (single col pass per wave, h' -> T0) ----
    // gi = C@W_ih^T + b_ih with C = (colsum(H) - H)/64; colsum commutes with
    // @W^T, so gi = (colsum(G) - G)/64 + b_ih, G = H@W_ih^T. Each wave owns
    // its 16 columns for all 64 rows: colsum = in-lane sum + shfl_xor(16,32).
    {
        const float bir = b_ih[n], biz = b_ih[n + 256], bin = b_ih[n + 512];
        const float bhr = b_hh[n], bhz = b_hh[n + 256], bhn = b_hh[n + 512];
        f32x4 gir[4] = {}, giz[4] = {}, gin[4] = {};
        f32x4 ghr[4] = {}, ghz[4] = {}, ghn[4] = {};
        #pragma unroll 4
        for (int k0 = 0; k0 < H0; k0 += 32) {
            const int kk = k0 + ko16;
            bf16x8 bir8 = w8(W_ih, (n      ) * H0 + kk);
            bf16x8 biz8 = w8(W_ih, (n + 256) * H0 + kk);
            bf16x8 bin8 = w8(W_ih, (n + 512) * H0 + kk);
            bf16x8 bhr8 = w8(W_hh, (n      ) * H0 + kk);
            bf16x8 bhz8 = w8(W_hh, (n + 256) * H0 + kk);
            bf16x8 bhn8 = w8(W_hh, (n + 512) * H0 + kk);
            #pragma unroll
            for (int rt = 0; rt < 4; rt++) {
                bf16x8 aH = *(const bf16x8*)&T1[tadr(rt * 16 + lc, kk)];
                gir[rt] = mfma16(aH, bir8, gir[rt]);
                giz[rt] = mfma16(aH, biz8, giz[rt]);
                gin[rt] = mfma16(aH, bin8, gin[rt]);
                ghr[rt] = mfma16(aH, bhr8, ghr[rt]);
                ghz[rt] = mfma16(aH, bhz8, ghz[rt]);
                ghn[rt] = mfma16(aH, bhn8, ghn[rt]);
            }
        }
        float Sr = 0.0f, Sz = 0.0f, Sn = 0.0f;
        #pragma unroll
        for (int rt = 0; rt < 4; rt++)
            #pragma unroll
            for (int i = 0; i < 4; i++) {
                Sr += gir[rt][i]; Sz += giz[rt][i]; Sn += gin[rt][i];
            }
        Sr += __shfl_xor(Sr, 16); Sr += __shfl_xor(Sr, 32);
        Sz += __shfl_xor(Sz, 16); Sz += __shfl_xor(Sz, 32);
        Sn += __shfl_xor(Sn, 16); Sn += __shfl_xor(Sn, 32);

        #pragma unroll
        for (int rt = 0; rt < 4; rt++)
            #pragma unroll
            for (int i = 0; i < 4; i++) {
                const int row = rt * 16 + quad * 4 + i;
                const float gi_r = (Sr - gir[rt][i]) * (1.0f / 64.0f) + bir;
                const float gi_z = (Sz - giz[rt][i]) * (1.0f / 64.0f) + biz;
                const float gi_n = (Sn - gin[rt][i]) * (1.0f / 64.0f) + bin;
                const float r  = fsigmoid(gi_r + ghr[rt][i] + bhr);
                const float z  = fsigmoid(gi_z + ghz[rt][i] + bhz);
                const float nn = ftanh(gi_n + r * (ghn[rt][i] + bhn));
                const float h  = bf2f(T1[tadr(row, n)]);
                T0[tadr(row, n)] = f2bf((1.0f - z) * nn + z * h);
            }
    }
    __syncthreads();

    // ---- value head: V = h' @ W_val^T + b_val -> T1 (H dead) ----
    {
        const float bias = b_val[n];
        f32x4 acc[4] = {};
        #pragma unroll
        for (int k0 = 0; k0 < H0; k0 += 32) {
            const int kk = k0 + ko16;
            bf16x8 b = w8(W_val, n * H0 + kk);
            #pragma unroll
            for (int rt = 0; rt < 4; rt++) {
                bf16x8 a = *(const bf16x8*)&T0[tadr(rt * 16 + lc, kk)];
                acc[rt] = mfma16(a, b, acc[rt]);
            }
        }
        #pragma unroll
        for (int rt = 0; rt < 4; rt++)
            #pragma unroll
            for (int i = 0; i < 4; i++) {
                const int row = rt * 16 + quad * 4 + i;
                T1[tadr(row, n)] = f2bf(acc[rt][i] + bias);
            }
    }
    __syncthreads();

    // ---- decode: OUT = V @ W_dec^T + b_dec -> global fp32 ----
    // 16 waves = 4 col-tiles x 4 row-tiles, one 16x16 out tile each.
    {
        const int ct = wave & 3;           // col tile (H2=64)
        const int rt = wave >> 2;          // row tile (64 rows)
        const int nd = ct * 16 + lc;
        const float bias = b_dec[nd];
        f32x4 acc = {};
        #pragma unroll
        for (int k0 = 0; k0 < H0; k0 += 32) {
            const int kk = k0 + ko16;
            bf16x8 b = w8(W_dec, nd * H0 + kk);
            bf16x8 a = *(const bf16x8*)&T1[tadr(rt * 16 + lc, kk)];
            acc = mfma16(a, b, acc);
        }
        #pragma unroll
        for (int i = 0; i < 4; i++) {
            const int row = rt * 16 + quad * 4 + i;
            out[(row0 + row) * 64 + nd] = acc[i] + bias;
        }
    }
}

extern "C" void kernel_launch(void* const* d_in, const int* in_sizes, int n_in,
                              void* d_out, int out_size, void* d_ws, size_t ws_size,
                              hipStream_t stream) {
    (void)in_sizes; (void)n_in; (void)out_size; (void)ws_size;
    const float* obs   = (const float*)d_in[0];
    const float* W_enc = (const float*)d_in[1];  const float* b_enc = (const float*)d_in[2];
    const float* W_obs = (const float*)d_in[3];  const float* b_obs = (const float*)d_in[4];
    const float* W_ih  = (const float*)d_in[5];  const float* b_ih  = (const float*)d_in[6];
    const float* W_hh  = (const float*)d_in[7];  const float* b_hh  = (const float*)d_in[8];
    const float* W_val = (const float*)d_in[9];  const float* b_val = (const float*)d_in[10];
    const float* W_dec = (const float*)d_in[11]; const float* b_dec = (const float*)d_in[12];
    float* out = (float*)d_out;
    __hip_bfloat16* ws = (__hip_bfloat16*)d_ws;

    prep_kernel<<<280, 256, 0, stream>>>(W_enc, W_obs, W_ih, W_hh, W_val, W_dec, ws);
    commnet_mfma<<<256, 1024, 0, stream>>>(
        ws, b_enc, b_obs, b_ih, b_hh, b_val, b_dec, obs, out);
}

// Round 18
// 124.582 us; speedup vs baseline: 1.4710x; 1.4710x over previous
//
#include <hip/hip_runtime.h>
#include <hip/hip_bf16.h>
#include <math.h>

// CommNetWork fused MFMA kernel v9, MI355X gfx950. fp32 in / fp32 out.
// v8 post-mortem: amdgpu_waves_per_eu(4,4) applied (SGPR 32->112) but VGPR
// stayed 64 -> 1024-thr workgroups are hard-capped at 64 VGPR on this
// toolchain (3 spellings tried). 1024-thr TLP path abandoned.
// v9 = proven v5 skeleton (512 thr, 116 VGPR, 44.2us) + EXACT val->dec
// fusion: OUT = (h'Wv^T+bv)Wd^T+bd == h'(WdWv)^T + (Wd bv + bd). prep
// computes W_fuse (64x256, fp32 accum -> bf16 once) and b_fuse in 64 extra
// blocks concurrent with the convert blocks. Main kernel drops the val
// stage: 5->4 barrier epochs, -11% FLOPs, -96KB/block L2 weight traffic.
// [Round 17: resubmitted verbatim - bench hit GPUAcquisitionTimeout; the v9
//  experiment has not yet been measured.]

typedef __bf16  bf16x8 __attribute__((ext_vector_type(8)));
typedef float   f32x4  __attribute__((ext_vector_type(4)));

#define DIN 128
#define H0  256
#define SW  264   // padded stride, 256-wide tiles: 132 dwords = 4 mod 32 banks
#define SWO 136   // padded stride, 128-wide obs tile
#define LOG2E 1.44269504088896f

// ws element offsets (bf16) for converted weight matrices
#define O_WENC  0
#define O_WOBS  32768
#define O_WIH   98304
#define O_WHH   294912
#define O_WFUSE 491520   // 64x256 fused W_dec@W_val
#define W_CONV  491520   // elements converted by prep (enc,obs,ih,hh)
#define NBLK_CONV 240    // W_CONV / (256*8)
#define O_BFUSE_B 1015808  // byte offset of b_fuse (f32[64]); ws total 1016064 B

__device__ __forceinline__ f32x4 mfma16(bf16x8 a, bf16x8 b, f32x4 c) {
    return __builtin_amdgcn_mfma_f32_16x16x32_bf16(a, b, c, 0, 0, 0);
}
__device__ __forceinline__ float bf2f(__hip_bfloat16 x) { return __bfloat162float(x); }
__device__ __forceinline__ __hip_bfloat16 f2bf(float x) { return __float2bfloat16(x); }

__device__ __forceinline__ float fsigmoid(float x) {
    float e = __builtin_amdgcn_exp2f(-LOG2E * x);
    return __builtin_amdgcn_rcpf(1.0f + e);
}
__device__ __forceinline__ float ftanh(float x) {
    float e = __builtin_amdgcn_exp2f(2.0f * LOG2E * x);
    return 1.0f - 2.0f * __builtin_amdgcn_rcpf(1.0f + e);
}

__device__ __forceinline__ bf16x8 w8(const __hip_bfloat16* p, int idx) {
    return *(const bf16x8*)(p + idx);
}

// affine tile addressing (padded stride)
__device__ __forceinline__ int tadr(int r, int k) { return r * SW + k; }
__device__ __forceinline__ int oadr(int r, int k) { return r * SWO + k; }

// ---- prep: convert 4 weight matrices fp32 -> bf16 (blocks 0..239) and
// ---- compute W_fuse = W_dec @ W_val, b_fuse = W_dec@b_val + b_dec
// ---- (blocks 240..303, one per output row o) ----
__global__ __launch_bounds__(256) void prep_kernel(
    const float* __restrict__ W_enc, const float* __restrict__ W_obs,
    const float* __restrict__ W_ih,  const float* __restrict__ W_hh,
    const float* __restrict__ W_val, const float* __restrict__ W_dec,
    const float* __restrict__ b_val, const float* __restrict__ b_dec,
    __hip_bfloat16* __restrict__ ws)
{
    const int blk = blockIdx.x;
    const int tid = threadIdx.x;
    if (blk < NBLK_CONV) {
        const int i = (blk * 256 + tid) * 8;
        const float* src; int off;
        if      (i < O_WOBS) { src = W_enc; off = O_WENC; }
        else if (i < O_WIH)  { src = W_obs; off = O_WOBS; }
        else if (i < O_WHH)  { src = W_ih;  off = O_WIH;  }
        else                 { src = W_hh;  off = O_WHH;  }
        const float* f = src + (i - off);
        f32x4 a = *(const f32x4*)f;
        f32x4 b = *(const f32x4*)(f + 4);
        bf16x8 v;
        #pragma unroll
        for (int j = 0; j < 4; j++) { v[j] = (__bf16)a[j]; v[j + 4] = (__bf16)b[j]; }
        *(bf16x8*)(ws + i) = v;
    } else {
        // fusion block: o = output row of W_fuse (0..63), tid = column k (0..255)
        const int o = blk - NBLK_CONV;
        __shared__ float wd[256];
        wd[tid] = W_dec[o * 256 + tid];
        __syncthreads();
        float acc = 0.0f;
        #pragma unroll 8
        for (int v = 0; v < 256; v++)
            acc += wd[v] * W_val[v * 256 + tid];   // coalesced over tid
        ws[O_WFUSE + o * 256 + tid] = f2bf(acc);
        if (tid < 64) {
            float p = 0.0f;
            #pragma unroll
            for (int v = tid; v < 256; v += 64) p += wd[v] * b_val[v];
            p += __shfl_xor(p, 32); p += __shfl_xor(p, 16); p += __shfl_xor(p, 8);
            p += __shfl_xor(p, 4);  p += __shfl_xor(p, 2);  p += __shfl_xor(p, 1);
            if (tid == 0) {
                float* bf = (float*)((char*)ws + O_BFUSE_B);
                bf[o] = p + b_dec[o];
            }
        }
    }
}

__global__ __launch_bounds__(512, 2) void commnet_mfma(
    const __hip_bfloat16* __restrict__ ws,
    const float* __restrict__ b_enc, const float* __restrict__ b_obs,
    const float* __restrict__ b_ih,  const float* __restrict__ b_hh,
    const float* __restrict__ obs,   float* __restrict__ out)
{
    __shared__ __align__(16) __hip_bfloat16 T0[64 * SW];  // X1 -> h'
    __shared__ __align__(16) __hip_bfloat16 T1[64 * SW];  // obs -> H

    const __hip_bfloat16* W_enc  = ws + O_WENC;
    const __hip_bfloat16* W_obs  = ws + O_WOBS;
    const __hip_bfloat16* W_ih   = ws + O_WIH;
    const __hip_bfloat16* W_hh   = ws + O_WHH;
    const __hip_bfloat16* W_fuse = ws + O_WFUSE;
    const float* b_fuse = (const float*)((const char*)ws + O_BFUSE_B);

    const int tid  = threadIdx.x;
    const int wave = tid >> 6;
    const int lane = tid & 63;
    const int quad = lane >> 4;
    const int lc   = lane & 15;          // tile col (n) / A-frag row (m)
    const int row0 = blockIdx.x * 64;    // global row base for this batch
    const int ko16 = quad * 8;           // k offset of this lane's fragment

    // ---- stage obs (fp32 global) -> bf16 padded T1 ----
    for (int i = tid; i < 64 * DIN / 8; i += 512) {
        const int r = i >> 4;
        const int c = (i & 15) << 3;
        const float* src = obs + (row0 + r) * DIN + c;
        f32x4 a = *(const f32x4*)src;
        f32x4 b = *(const f32x4*)(src + 4);
        bf16x8 v;
        #pragma unroll
        for (int j = 0; j < 4; j++) { v[j] = (__bf16)a[j]; v[j + 4] = (__bf16)b[j]; }
        *(bf16x8*)&T1[oadr(r, c)] = v;
    }
    __syncthreads();

    // ---- stage 1: X1 = relu(obs @ W_enc^T + b_enc) -> T0 (2 col passes) ----
    #pragma unroll
    for (int cp = 0; cp < 2; cp++) {
        const int n = (wave + 8 * cp) * 16 + lc;
        const float bias = b_enc[n];
        f32x4 acc[4] = {};
        #pragma unroll
        for (int k0 = 0; k0 < DIN; k0 += 32) {
            const int kk = k0 + ko16;
            bf16x8 b = w8(W_enc, n * DIN + kk);
            #pragma unroll
            for (int rt = 0; rt < 4; rt++) {
                bf16x8 a = *(const bf16x8*)&T1[oadr(rt * 16 + lc, kk)];
                acc[rt] = mfma16(a, b, acc[rt]);
            }
        }
        #pragma unroll
        for (int rt = 0; rt < 4; rt++)
            #pragma unroll
            for (int i = 0; i < 4; i++) {
                const int row = rt * 16 + quad * 4 + i;
                T0[tadr(row, n)] = f2bf(fmaxf(acc[rt][i] + bias, 0.0f));
            }
    }
    __syncthreads();

    // ---- stage 2: H = X1 @ W_obs^T + b_obs -> T1 (obs dead) ----
    #pragma unroll
    for (int cp = 0; cp < 2; cp++) {
        const int n = (wave + 8 * cp) * 16 + lc;
        const float bias = b_obs[n];
        f32x4 acc[4] = {};
        #pragma unroll
        for (int k0 = 0; k0 < H0; k0 += 32) {
            const int kk = k0 + ko16;
            bf16x8 b = w8(W_obs, n * H0 + kk);
            #pragma unroll
            for (int rt = 0; rt < 4; rt++) {
                bf16x8 a = *(const bf16x8*)&T0[tadr(rt * 16 + lc, kk)];
                acc[rt] = mfma16(a, b, acc[rt]);
            }
        }
        #pragma unroll
        for (int rt = 0; rt < 4; rt++)
            #pragma unroll
            for (int i = 0; i < 4; i++) {
                const int row = rt * 16 + quad * 4 + i;
                T1[tadr(row, n)] = f2bf(acc[rt][i] + bias);
            }
    }
    __syncthreads();

    // ---- GRU with folded comm (2 col passes, h' -> T0) ----
    // gi = C@W_ih^T + b_ih with C = (colsum(H) - H)/64; colsum commutes with
    // @W^T, so gi = (colsum(G) - G)/64 + b_ih, G = H@W_ih^T. Each wave owns
    // its 16 columns for all 64 rows: colsum = in-lane sum + shfl_xor(16,32).
    #pragma unroll
    for (int cp = 0; cp < 2; cp++) {
        const int n = (wave + 8 * cp) * 16 + lc;
        const float bir = b_ih[n], biz = b_ih[n + 256], bin = b_ih[n + 512];
        const float bhr = b_hh[n], bhz = b_hh[n + 256], bhn = b_hh[n + 512];
        f32x4 gir[4] = {}, giz[4] = {}, gin[4] = {};
        f32x4 ghr[4] = {}, ghz[4] = {}, ghn[4] = {};
        #pragma unroll 4
        for (int k0 = 0; k0 < H0; k0 += 32) {
            const int kk = k0 + ko16;
            bf16x8 bir8 = w8(W_ih, (n      ) * H0 + kk);
            bf16x8 biz8 = w8(W_ih, (n + 256) * H0 + kk);
            bf16x8 bin8 = w8(W_ih, (n + 512) * H0 + kk);
            bf16x8 bhr8 = w8(W_hh, (n      ) * H0 + kk);
            bf16x8 bhz8 = w8(W_hh, (n + 256) * H0 + kk);
            bf16x8 bhn8 = w8(W_hh, (n + 512) * H0 + kk);
            #pragma unroll
            for (int rt = 0; rt < 4; rt++) {
                bf16x8 aH = *(const bf16x8*)&T1[tadr(rt * 16 + lc, kk)];
                gir[rt] = mfma16(aH, bir8, gir[rt]);
                giz[rt] = mfma16(aH, biz8, giz[rt]);
                gin[rt] = mfma16(aH, bin8, gin[rt]);
                ghr[rt] = mfma16(aH, bhr8, ghr[rt]);
                ghz[rt] = mfma16(aH, bhz8, ghz[rt]);
                ghn[rt] = mfma16(aH, bhn8, ghn[rt]);
            }
        }
        float Sr = 0.0f, Sz = 0.0f, Sn = 0.0f;
        #pragma unroll
        for (int rt = 0; rt < 4; rt++)
            #pragma unroll
            for (int i = 0; i < 4; i++) {
                Sr += gir[rt][i]; Sz += giz[rt][i]; Sn += gin[rt][i];
            }
        Sr += __shfl_xor(Sr, 16); Sr += __shfl_xor(Sr, 32);
        Sz += __shfl_xor(Sz, 16); Sz += __shfl_xor(Sz, 32);
        Sn += __shfl_xor(Sn, 16); Sn += __shfl_xor(Sn, 32);

        #pragma unroll
        for (int rt = 0; rt < 4; rt++)
            #pragma unroll
            for (int i = 0; i < 4; i++) {
                const int row = rt * 16 + quad * 4 + i;
                const float gi_r = (Sr - gir[rt][i]) * (1.0f / 64.0f) + bir;
                const float gi_z = (Sz - giz[rt][i]) * (1.0f / 64.0f) + biz;
                const float gi_n = (Sn - gin[rt][i]) * (1.0f / 64.0f) + bin;
                const float r  = fsigmoid(gi_r + ghr[rt][i] + bhr);
                const float z  = fsigmoid(gi_z + ghz[rt][i] + bhz);
                const float nn = ftanh(gi_n + r * (ghn[rt][i] + bhn));
                const float h  = bf2f(T1[tadr(row, n)]);
                T0[tadr(row, n)] = f2bf((1.0f - z) * nn + z * h);
            }
    }
    __syncthreads();

    // ---- decode (fused): OUT = h' @ W_fuse^T + b_fuse -> global fp32 ----
    {
        const int ct  = wave & 3;          // 4 col-tiles (H2=64)
        const int rtb = (wave >> 2) * 2;   // waves 0-3: rows 0..31, 4-7: 32..63
        const int nd  = ct * 16 + lc;
        const float bias = b_fuse[nd];
        f32x4 acc[2] = {};
        #pragma unroll
        for (int k0 = 0; k0 < H0; k0 += 32) {
            const int kk = k0 + ko16;
            bf16x8 b = w8(W_fuse, nd * H0 + kk);
            #pragma unroll
            for (int j = 0; j < 2; j++) {
                bf16x8 a = *(const bf16x8*)&T0[tadr((rtb + j) * 16 + lc, kk)];
                acc[j] = mfma16(a, b, acc[j]);
            }
        }
        #pragma unroll
        for (int j = 0; j < 2; j++)
            #pragma unroll
            for (int i = 0; i < 4; i++) {
                const int row = (rtb + j) * 16 + quad * 4 + i;
                out[(row0 + row) * 64 + nd] = acc[j][i] + bias;
            }
    }
}

extern "C" void kernel_launch(void* const* d_in, const int* in_sizes, int n_in,
                              void* d_out, int out_size, void* d_ws, size_t ws_size,
                              hipStream_t stream) {
    (void)in_sizes; (void)n_in; (void)out_size; (void)ws_size;
    const float* obs   = (const float*)d_in[0];
    const float* W_enc = (const float*)d_in[1];  const float* b_enc = (const float*)d_in[2];
    const float* W_obs = (const float*)d_in[3];  const float* b_obs = (const float*)d_in[4];
    const float* W_ih  = (const float*)d_in[5];  const float* b_ih  = (const float*)d_in[6];
    const float* W_hh  = (const float*)d_in[7];  const float* b_hh  = (const float*)d_in[8];
    const float* W_val = (const float*)d_in[9];  const float* b_val = (const float*)d_in[10];
    const float* W_dec = (const float*)d_in[11]; const float* b_dec = (const float*)d_in[12];
    float* out = (float*)d_out;
    __hip_bfloat16* ws = (__hip_bfloat16*)d_ws;

    prep_kernel<<<NBLK_CONV + 64, 256, 0, stream>>>(
        W_enc, W_obs, W_ih, W_hh, W_val, W_dec, b_val, b_dec, ws);
    commnet_mfma<<<256, 512, 0, stream>>>(
        ws, b_enc, b_obs, b_ih, b_hh, obs, out);
}